// Round 8
// baseline (91.914 us; speedup 1.0000x reference)
//
#include <hip/hip_runtime.h>
#include <hip/hip_fp16.h>

typedef __attribute__((ext_vector_type(8)))  _Float16 half8;
typedef __attribute__((ext_vector_type(16))) float    f32x16;

#define B_   16
#define NPTS 4096                      // points per batch (N == M == 4096)

constexpr int BLK  = 512;              // 8 waves per block
constexpr int WV   = 8;
constexpr int QF   = 2;                // query fragments per wave (64 queries)
constexpr int TF   = 2;                // target tiles per loop step
constexpr int QPW  = 32 * QF;          // 64 queries per wave
constexpr int TSPL = 2;                // target splits (waves sharing a query group)
constexpr int QG   = WV / TSPL;        // 4 query groups per block
constexpr int QPB  = QG * QPW;         // 256 queries per block
constexpr int NQC  = NPTS / QPB;       // 16 query chunks
constexpr int TPS  = NPTS / TSPL;      // 2048 targets per split
constexpr int TPW  = TPS / 32;         // 64 tiles of 32 targets per wave
constexpr int NIT  = TPW / TF;         // 32 loop steps (2 tiles each)
constexpr int NBLK = 2 * B_ * NQC;     // 512 blocks (2 per CU)

__device__ __forceinline__ float min3f(float a, float b, float c) {
    return fminf(fminf(a, b), c);      // -> v_min3_f32
}

__device__ __forceinline__ float tree16(const f32x16& d) {
    float a0 = min3f(d[0],  d[1],  d[2]);
    float a1 = min3f(d[3],  d[4],  d[5]);
    float a2 = min3f(d[6],  d[7],  d[8]);
    float a3 = min3f(d[9],  d[10], d[11]);
    float a4 = min3f(d[12], d[13], d[14]);
    return fminf(min3f(a0, a1, a2), min3f(a3, a4, d[15]));
}

// ------------------------------------------------------------------
// R8 = CALIBRATION ROUND. Five scheduling levers (TLP x2, ILP x2, ILP
// x4, LDS prefetch, setprio) were all null; kernel stuck ~30us vs ~5-10us
// pipe floors, and its counters are invisible (below the 40us harness
// fill in top-5). This round measures the sweep phase by running it
// TWICE into the same running min (min(x,x)=x -> bitwise-identical
// output). An asm-laundered zero index (rule #17) defeats MFMA/load CSE
// so pass 2 really executes. dur delta vs R7 = sweep cost.
//   Case A (sweep-dominant): bench ~100-107 -> attack inner-loop codegen.
//   Case B (sweep-minor):    bench ~83-88   -> attack stage/launch/tail.
// Structure otherwise = proven R4 envelope + float4 staging.
__global__ __launch_bounds__(BLK, 4) void chamfer_mfma(
        const float* __restrict__ pred, const float* __restrict__ gt,
        float* __restrict__ accum, unsigned* __restrict__ counter,
        float* __restrict__ out) {
    const int qc  = blockIdx.x;
    const int b   = blockIdx.y;
    const int dir = blockIdx.z;
    const float* qsrc = dir ? gt   : pred;   // queries
    const float* tsrc = dir ? pred : gt;     // targets

    __shared__ uint4 sh[NPTS];               // 64 KB: all targets as A-frag rows
    __shared__ float sred[WV][QPW];          // 2 KB: per-wave per-query min d^2
    __shared__ float ps[QG];

    const int tid  = threadIdx.x;
    const int lane = tid & 63;
    const int wv   = tid >> 6;
    const int m    = lane & 31;
    const int qg   = wv >> 1;                // query group 0..3
    const int ts   = wv & 1;                 // target split 0..1

    // ---- B fragments: this lane's two queries (cols m and m+32) ----
    const float* qbase = qsrc + (b * NPTS + qc * QPB + qg * QPW) * 3;
    half8 bfrag[QF];
    float q2[QF];
#pragma unroll
    for (int f = 0; f < QF; ++f) {
        const float* qp = qbase + (f * 32 + m) * 3;
        __half hqx = __float2half(qp[0]);
        __half hqy = __float2half(qp[1]);
        __half hqz = __float2half(qp[2]);
        float fqx = __half2float(hqx), fqy = __half2float(hqy), fqz = __half2float(hqz);
        q2[f] = fmaf(fqx, fqx, fmaf(fqy, fqy, fqz * fqz));
        uint4 bu;
        bu.x = (unsigned)__half_as_ushort(hqx) | ((unsigned)__half_as_ushort(hqy) << 16);
        bu.y = (unsigned)__half_as_ushort(hqz) | (0x3C00u << 16);   // {z, 1.0}
        bu.z = 0x3C00u;                                             // {1.0, 0}
        bu.w = 0u;
        bfrag[f] = __builtin_bit_cast(half8, bu);
    }

    f32x16 zero;
#pragma unroll
    for (int i = 0; i < 16; ++i) zero[i] = 0.0f;

    // ---- stage ALL 4096 targets as A-frag rows (float4-vectorized) ----
    const float4* tp4 = reinterpret_cast<const float4*>(tsrc + b * NPTS * 3);
#pragma unroll
    for (int k = 0; k < NPTS / (4 * BLK); ++k) {    // 2 super-iters x 4 points
        const int tq = k * BLK + tid;               // quad index
        const float4 f0 = tp4[tq * 3 + 0];
        const float4 f1 = tp4[tq * 3 + 1];
        const float4 f2 = tp4[tq * 3 + 2];
        const float px[4] = {f0.x, f0.w, f1.z, f2.y};
        const float py[4] = {f0.y, f1.x, f1.w, f2.z};
        const float pz[4] = {f0.z, f1.y, f2.x, f2.w};
#pragma unroll
        for (int i = 0; i < 4; ++i) {
            __half hx = __float2half(px[i]);
            __half hy = __float2half(py[i]);
            __half hz = __float2half(pz[i]);
            float fx = __half2float(hx), fy = __half2float(hy), fz = __half2float(hz);
            float g2 = fmaf(fx, fx, fmaf(fy, fy, fz * fz));
            __half ax = __float2half(-2.0f * fx);
            __half ay = __float2half(-2.0f * fy);
            __half az = __float2half(-2.0f * fz);
            __half g2hi = __float2half(g2);
            __half g2lo = __float2half(g2 - __half2float(g2hi));
            uint4 w;
            w.x = (unsigned)__half_as_ushort(ax) | ((unsigned)__half_as_ushort(ay) << 16);
            w.y = (unsigned)__half_as_ushort(az) | ((unsigned)__half_as_ushort(g2hi) << 16);
            w.z = (unsigned)__half_as_ushort(g2lo);
            w.w = 0u;
            sh[tq * 4 + i] = w;
        }
    }
    __syncthreads();

    const uint4* shp = sh + ts * TPS + m;    // lane base (lanes L, L+32 share addr)
    float mn0 = 1e30f, mn1 = 1e30f;

    // ---- sweep PASS 1 (the real work) ----
#pragma unroll 8
    for (int t = 0; t < NIT; ++t) {
        uint4 au0 = shp[t * 64];             // tile 2t
        uint4 au1 = shp[t * 64 + 32];        // tile 2t+1
        half8 a0 = __builtin_bit_cast(half8, au0);
        half8 a1 = __builtin_bit_cast(half8, au1);
        f32x16 d00 = __builtin_amdgcn_mfma_f32_32x32x16_f16(a0, bfrag[0], zero, 0, 0, 0);
        f32x16 d01 = __builtin_amdgcn_mfma_f32_32x32x16_f16(a0, bfrag[1], zero, 0, 0, 0);
        f32x16 d10 = __builtin_amdgcn_mfma_f32_32x32x16_f16(a1, bfrag[0], zero, 0, 0, 0);
        f32x16 d11 = __builtin_amdgcn_mfma_f32_32x32x16_f16(a1, bfrag[1], zero, 0, 0, 0);
        float t00 = tree16(d00);
        float t01 = tree16(d01);
        float t10 = tree16(d10);
        float t11 = tree16(d11);
        mn0 = min3f(mn0, t00, t10);
        mn1 = min3f(mn1, t01, t11);
    }

    // ---- launder a zero offset so pass 2 cannot be CSE'd away ----
    int zofs = 0;
    asm volatile("" : "+v"(zofs));

    // ---- sweep PASS 2 (identical work; min(x,x)=x -> output unchanged) ----
#pragma unroll 8
    for (int t = 0; t < NIT; ++t) {
        uint4 au0 = shp[zofs + t * 64];
        uint4 au1 = shp[zofs + t * 64 + 32];
        half8 a0 = __builtin_bit_cast(half8, au0);
        half8 a1 = __builtin_bit_cast(half8, au1);
        f32x16 d00 = __builtin_amdgcn_mfma_f32_32x32x16_f16(a0, bfrag[0], zero, 0, 0, 0);
        f32x16 d01 = __builtin_amdgcn_mfma_f32_32x32x16_f16(a0, bfrag[1], zero, 0, 0, 0);
        f32x16 d10 = __builtin_amdgcn_mfma_f32_32x32x16_f16(a1, bfrag[0], zero, 0, 0, 0);
        f32x16 d11 = __builtin_amdgcn_mfma_f32_32x32x16_f16(a1, bfrag[1], zero, 0, 0, 0);
        float t00 = tree16(d00);
        float t01 = tree16(d01);
        float t10 = tree16(d10);
        float t11 = tree16(d11);
        mn0 = min3f(mn0, t00, t10);
        mn1 = min3f(mn1, t01, t11);
    }

    // rows split across lane halves: full 32-row min needs lane ^ 32
    float v0 = fminf(mn0, __shfl_xor(mn0, 32));
    float v1 = fminf(mn1, __shfl_xor(mn1, 32));
    float dd0 = fmaxf(fmaf(0.5f, v0, q2[0]), 0.0f);  // undo K-dup, fold |q|^2
    float dd1 = fmaxf(fmaf(0.5f, v1, q2[1]), 0.0f);
    if (lane < 32) {                                 // lanes 32-63 hold duplicates
        sred[wv][m]      = dd0;
        sred[wv][m + 32] = dd1;
    }
    __syncthreads();

    // ---- combine 2 target splits per query, sqrt, block-sum ----
    float s = 0.0f;
    if (wv < QG) {                               // threads 0..255 = 256 queries
        const int g  = wv;                       // query group 0..3
        const int mm = lane;                     // query within group 0..63
        float d = fminf(sred[g * 2 + 0][mm], sred[g * 2 + 1][mm]);
        s = sqrtf(d);
        // butterfly sum over this wave's 64 lanes
#pragma unroll
        for (int off = 32; off; off >>= 1) s += __shfl_xor(s, off);
        if (lane == 0) ps[g] = s;
    }
    __syncthreads();

    if (tid == 0) {
        float bs = ps[0] + ps[1] + ps[2] + ps[3];
        atomicAdd(accum, bs);
        __threadfence();
        if (atomicAdd(counter, 1u) == NBLK - 1) {   // last block finalizes
            float total = atomicAdd(accum, 0.0f);   // coherent read
            float loss  = total * (1.0f / (float)(B_ * NPTS));
            out[0] = loss;          // WEIGHT * loss, WEIGHT = 1
            out[1] = loss;          // helper_loss
            out[2] = 0.1f * loss;   // helper_cderr = p1 chamfer * xyz_unit
        }
    }
}

// ------------------------------------------------------------------
extern "C" void kernel_launch(void* const* d_in, const int* in_sizes, int n_in,
                              void* d_out, int out_size, void* d_ws, size_t ws_size,
                              hipStream_t stream) {
    const float* pred = (const float*)d_in[0];
    const float* gt   = (const float*)d_in[1];
    float*    out     = (float*)d_out;
    float*    accum   = (float*)d_ws;
    unsigned* counter = (unsigned*)d_ws + 1;

    hipMemsetAsync(d_ws, 0, 8, stream);
    chamfer_mfma<<<dim3(NQC, B_, 2), BLK, 0, stream>>>(pred, gt, accum, counter, out);
}

// Round 9
// 80.240 us; speedup vs baseline: 1.1455x; 1.1455x over previous
//
#include <hip/hip_runtime.h>
#include <hip/hip_fp16.h>

typedef __attribute__((ext_vector_type(8)))  _Float16 half8;
typedef __attribute__((ext_vector_type(16))) float    f32x16;

#define B_   16
#define NPTS 4096                      // points per batch (N == M == 4096)

constexpr int BLK  = 512;              // 8 waves per block
constexpr int WV   = 8;
constexpr int QF   = 2;                // query fragments per wave (64 queries)
constexpr int TF   = 2;                // target tiles per loop step
constexpr int QPW  = 32 * QF;          // 64 queries per wave
constexpr int TSPL = 2;                // target splits (waves sharing a query group)
constexpr int QG   = WV / TSPL;        // 4 query groups per block
constexpr int QPB  = QG * QPW;         // 256 queries per block
constexpr int NQC  = NPTS / QPB;       // 16 query chunks
constexpr int TPS  = NPTS / TSPL;      // 2048 targets per split
constexpr int TPW  = TPS / 32;         // 64 tiles of 32 targets per wave
constexpr int NIT  = TPW / TF;         // 32 loop steps (2 tiles each)
constexpr int NBLK = 2 * B_ * NQC;     // 512 blocks (2 per CU)

__device__ __forceinline__ float min3f(float a, float b, float c) {
    return fminf(fminf(a, b), c);      // -> v_min3_f32
}

__device__ __forceinline__ float tree16(const f32x16& d) {
    float a0 = min3f(d[0],  d[1],  d[2]);
    float a1 = min3f(d[3],  d[4],  d[5]);
    float a2 = min3f(d[6],  d[7],  d[8]);
    float a3 = min3f(d[9],  d[10], d[11]);
    float a4 = min3f(d[12], d[13], d[14]);
    return fminf(min3f(a0, a1, a2), min3f(a3, a4, d[15]));
}

// ------------------------------------------------------------------
// R9: LDS return-path dedup. R8 calibration: sweep ~= 13us of the ~31us
// kernel, LDS ds_read is the largest pipe term (per-CU 12.3k cyc/pass)
// -- and HALF of every ds_read_b128's bytes were redundant (lanes L and
// L+32 fetched the same 16B, the K-dup broadcast). Fix WITHOUT lane
// masking (R6 disaster): one ds_read_b128 reads 64 DISTINCT rows
// (2 tiles); 4x v_permlane32_swap_b32 reconstruct both duplicated-half
// A-fragments in registers:
//     swap(xa=au, xb=au): xa = [au.lo|au.lo] (tile 2t, = old au0)
//                         xb = [au.hi|au.hi] (tile 2t+1, = old au1)
// MFMA inputs bitwise identical to R4; ds_reads/wave halve (64->32).
// Staging reverted to R4 scalar loads (float4 staging's sh[4t+i] write
// pattern caused the 786K bank conflicts seen in R8 -> back to 0).
// Math identical: A-row [-2x,-2y,-2z,g2hi,g2lo,0,0,0], B-frag
// [x,y,z,1,1,0,0,0] -> D = 2(|g|^2 - 2 q.g); d^2 = 0.5*minD + |q|^2.
__global__ __launch_bounds__(BLK, 4) void chamfer_mfma(
        const float* __restrict__ pred, const float* __restrict__ gt,
        float* __restrict__ accum, unsigned* __restrict__ counter,
        float* __restrict__ out) {
    const int qc  = blockIdx.x;
    const int b   = blockIdx.y;
    const int dir = blockIdx.z;
    const float* qsrc = dir ? gt   : pred;   // queries
    const float* tsrc = dir ? pred : gt;     // targets

    __shared__ uint4 sh[NPTS];               // 64 KB: all targets as A-frag rows
    __shared__ float sred[WV][QPW];          // 2 KB: per-wave per-query min d^2
    __shared__ float ps[QG];

    const int tid  = threadIdx.x;
    const int lane = tid & 63;
    const int wv   = tid >> 6;
    const int m    = lane & 31;
    const int qg   = wv >> 1;                // query group 0..3
    const int ts   = wv & 1;                 // target split 0..1

    // ---- B fragments: this lane's two queries (cols m and m+32) ----
    const float* qbase = qsrc + (b * NPTS + qc * QPB + qg * QPW) * 3;
    half8 bfrag[QF];
    float q2[QF];
#pragma unroll
    for (int f = 0; f < QF; ++f) {
        const float* qp = qbase + (f * 32 + m) * 3;
        __half hqx = __float2half(qp[0]);
        __half hqy = __float2half(qp[1]);
        __half hqz = __float2half(qp[2]);
        float fqx = __half2float(hqx), fqy = __half2float(hqy), fqz = __half2float(hqz);
        q2[f] = fmaf(fqx, fqx, fmaf(fqy, fqy, fqz * fqz));
        uint4 bu;
        bu.x = (unsigned)__half_as_ushort(hqx) | ((unsigned)__half_as_ushort(hqy) << 16);
        bu.y = (unsigned)__half_as_ushort(hqz) | (0x3C00u << 16);   // {z, 1.0}
        bu.z = 0x3C00u;                                             // {1.0, 0}
        bu.w = 0u;
        bfrag[f] = __builtin_bit_cast(half8, bu);
    }

    f32x16 zero;
#pragma unroll
    for (int i = 0; i < 16; ++i) zero[i] = 0.0f;

    // ---- stage ALL 4096 targets as A-frag rows (R4 pattern: scalar
    //      loads, conflict-free consecutive ds_write_b128) ----
    const float* tp = tsrc + b * NPTS * 3;
#pragma unroll
    for (int k = 0; k < NPTS / BLK; ++k) {   // 8 points / thread
        int j = k * BLK + tid;
        __half hx = __float2half(tp[3 * j + 0]);
        __half hy = __float2half(tp[3 * j + 1]);
        __half hz = __float2half(tp[3 * j + 2]);
        float fx = __half2float(hx), fy = __half2float(hy), fz = __half2float(hz);
        float g2 = fmaf(fx, fx, fmaf(fy, fy, fz * fz));
        __half ax = __float2half(-2.0f * fx);
        __half ay = __float2half(-2.0f * fy);
        __half az = __float2half(-2.0f * fz);
        __half g2hi = __float2half(g2);
        __half g2lo = __float2half(g2 - __half2float(g2hi));
        uint4 w;
        w.x = (unsigned)__half_as_ushort(ax) | ((unsigned)__half_as_ushort(ay) << 16);
        w.y = (unsigned)__half_as_ushort(az) | ((unsigned)__half_as_ushort(g2hi) << 16);
        w.z = (unsigned)__half_as_ushort(g2lo);
        w.w = 0u;
        sh[j] = w;
    }
    __syncthreads();

    // ---- sweep: 1 ds_read_b128 (64 distinct rows = 2 tiles) + 4
    //      permlane32_swap to build both A-frags + 4 MFMAs per step ----
    const uint4* shp2 = sh + ts * TPS + lane;   // 64 distinct rows per read
    float mn0 = 1e30f, mn1 = 1e30f;
#pragma unroll 8
    for (int t = 0; t < NIT; ++t) {
        uint4 au = shp2[t * 64];             // rows t*64 .. t*64+63 (byte off t*1024)
        uint4 xa = au, xb = au;
        asm volatile("v_permlane32_swap_b32 %0, %1" : "+v"(xa.x), "+v"(xb.x));
        asm volatile("v_permlane32_swap_b32 %0, %1" : "+v"(xa.y), "+v"(xb.y));
        asm volatile("v_permlane32_swap_b32 %0, %1" : "+v"(xa.z), "+v"(xb.z));
        asm volatile("v_permlane32_swap_b32 %0, %1" : "+v"(xa.w), "+v"(xb.w));
        half8 a0 = __builtin_bit_cast(half8, xa);   // tile 2t   (dup halves)
        half8 a1 = __builtin_bit_cast(half8, xb);   // tile 2t+1 (dup halves)
        f32x16 d00 = __builtin_amdgcn_mfma_f32_32x32x16_f16(a0, bfrag[0], zero, 0, 0, 0);
        f32x16 d01 = __builtin_amdgcn_mfma_f32_32x32x16_f16(a0, bfrag[1], zero, 0, 0, 0);
        f32x16 d10 = __builtin_amdgcn_mfma_f32_32x32x16_f16(a1, bfrag[0], zero, 0, 0, 0);
        f32x16 d11 = __builtin_amdgcn_mfma_f32_32x32x16_f16(a1, bfrag[1], zero, 0, 0, 0);
        float t00 = tree16(d00);
        float t01 = tree16(d01);
        float t10 = tree16(d10);
        float t11 = tree16(d11);
        mn0 = min3f(mn0, t00, t10);
        mn1 = min3f(mn1, t01, t11);
    }

    // rows split across lane halves: full 32-row min needs lane ^ 32
    float v0 = fminf(mn0, __shfl_xor(mn0, 32));
    float v1 = fminf(mn1, __shfl_xor(mn1, 32));
    float dd0 = fmaxf(fmaf(0.5f, v0, q2[0]), 0.0f);  // undo K-dup, fold |q|^2
    float dd1 = fmaxf(fmaf(0.5f, v1, q2[1]), 0.0f);
    if (lane < 32) {                                 // lanes 32-63 hold duplicates
        sred[wv][m]      = dd0;
        sred[wv][m + 32] = dd1;
    }
    __syncthreads();

    // ---- combine 2 target splits per query, sqrt, block-sum ----
    float s = 0.0f;
    if (wv < QG) {                               // threads 0..255 = 256 queries
        const int g  = wv;                       // query group 0..3
        const int mm = lane;                     // query within group 0..63
        float d = fminf(sred[g * 2 + 0][mm], sred[g * 2 + 1][mm]);
        s = sqrtf(d);
        // butterfly sum over this wave's 64 lanes
#pragma unroll
        for (int off = 32; off; off >>= 1) s += __shfl_xor(s, off);
        if (lane == 0) ps[g] = s;
    }
    __syncthreads();

    if (tid == 0) {
        float bs = ps[0] + ps[1] + ps[2] + ps[3];
        atomicAdd(accum, bs);
        __threadfence();
        if (atomicAdd(counter, 1u) == NBLK - 1) {   // last block finalizes
            float total = atomicAdd(accum, 0.0f);   // coherent read
            float loss  = total * (1.0f / (float)(B_ * NPTS));
            out[0] = loss;          // WEIGHT * loss, WEIGHT = 1
            out[1] = loss;          // helper_loss
            out[2] = 0.1f * loss;   // helper_cderr = p1 chamfer * xyz_unit
        }
    }
}

// ------------------------------------------------------------------
extern "C" void kernel_launch(void* const* d_in, const int* in_sizes, int n_in,
                              void* d_out, int out_size, void* d_ws, size_t ws_size,
                              hipStream_t stream) {
    const float* pred = (const float*)d_in[0];
    const float* gt   = (const float*)d_in[1];
    float*    out     = (float*)d_out;
    float*    accum   = (float*)d_ws;
    unsigned* counter = (unsigned*)d_ws + 1;

    hipMemsetAsync(d_ws, 0, 8, stream);
    chamfer_mfma<<<dim3(NQC, B_, 2), BLK, 0, stream>>>(pred, gt, accum, counter, out);
}